// Round 1
// baseline (1083.172 us; speedup 1.0000x reference)
//
#include <hip/hip_runtime.h>
#include <math.h>

#define NROWS 131072
#define HID 256
#define NPAR 800        // 32 * 25
#define RPB 16          // rows per block
#define HALF_C 400      // GEMM2 columns per pass (16 d-groups * 25)
#define HALF_D 16       // transform dims per pass

__global__ __launch_bounds__(256)
void rqs_fused(const float* __restrict__ inp,
               const float* __restrict__ W1,
               const float* __restrict__ b1,
               const float* __restrict__ W2,
               const float* __restrict__ b2,
               float* __restrict__ out)
{
    __shared__ float ht[HID][RPB];        // h transposed, 16 KiB
    __shared__ float p_lds[RPB][HALF_C];  // params half-tile, 25.6 KiB

    const int t = threadIdx.x;
    const int row0 = blockIdx.x * RPB;

    // ---- identity pass-through (cols 0..31) ----
    for (int idx = t; idx < RPB * 32; idx += 256) {
        int r = idx >> 5, c = idx & 31;
        out[(size_t)(row0 + r) * 64 + c] = inp[(size_t)(row0 + r) * 64 + c];
    }

    // ---- GEMM1: h = relu(x_id @ W1 + b1), thread t <-> hidden col j = t ----
    {
        const int j = t;
        float w1v[32];
#pragma unroll
        for (int k = 0; k < 32; ++k) w1v[k] = W1[k * HID + j];
        const float bj = b1[j];
        for (int r = 0; r < RPB; ++r) {
            const float* xr = inp + (size_t)(row0 + r) * 64;  // uniform -> scalar loads
            float s = bj;
#pragma unroll
            for (int k = 0; k < 32; ++k) s = fmaf(xr[k], w1v[k], s);
            ht[j][r] = fmaxf(s, 0.0f);
        }
    }
    __syncthreads();

    float ladsum = 0.0f;
    const int r_e = t >> 4;   // epilogue row (0..15)
    const int dl  = t & 15;   // epilogue d within pass

    for (int pass = 0; pass < 2; ++pass) {
        // ---- GEMM2 half: params cols [pass*400, pass*400+400) ----
        for (int c = t; c < HALF_C; c += 256) {
            const int cg = pass * HALF_C + c;
            float acc[RPB];
            const float bc = b2[cg];
#pragma unroll
            for (int r = 0; r < RPB; ++r) acc[r] = bc;
            const float* w2p = W2 + cg;
#pragma unroll 4
            for (int k = 0; k < HID; ++k) {
                const float wv = w2p[(size_t)k * NPAR];
                const float4* hp = (const float4*)(&ht[k][0]);
                float hbuf[RPB];
                *(float4*)&hbuf[0]  = hp[0];
                *(float4*)&hbuf[4]  = hp[1];
                *(float4*)&hbuf[8]  = hp[2];
                *(float4*)&hbuf[12] = hp[3];
#pragma unroll
                for (int r = 0; r < RPB; ++r) acc[r] = fmaf(hbuf[r], wv, acc[r]);
            }
#pragma unroll
            for (int r = 0; r < RPB; ++r) p_lds[r][c] = acc[r];
        }
        __syncthreads();

        // ---- epilogue for d = pass*16 + dl : one (row, d) per thread ----
        {
            const int d = pass * HALF_D + dl;
            const float* p = &p_lds[r_e][dl * 25];
            float pv[25];
#pragma unroll
            for (int j = 0; j < 25; ++j) pv[j] = p[j];

            // softmax(un_w) -> widths -> cw[9]
            float cw[9], ch[9], dd[9];
            {
                float mw = pv[0];
#pragma unroll
                for (int j = 1; j < 8; ++j) mw = fmaxf(mw, pv[j]);
                float e[8], sw = 0.f;
#pragma unroll
                for (int j = 0; j < 8; ++j) { e[j] = __expf(pv[j] - mw); sw += e[j]; }
                const float scale = 0.992f / sw;   // (1 - MIN_W*K)/sum
                float run = 0.f;
                cw[0] = 0.f;
#pragma unroll
                for (int j = 0; j < 8; ++j) { run += 0.001f + e[j] * scale; cw[j + 1] = run; }
                const float icn = 1.0f / fmaxf(cw[8], 1e-12f);
#pragma unroll
                for (int j = 1; j <= 8; ++j) cw[j] *= icn;
            }
            {
                float mh = pv[8];
#pragma unroll
                for (int j = 1; j < 8; ++j) mh = fmaxf(mh, pv[8 + j]);
                float e[8], sh = 0.f;
#pragma unroll
                for (int j = 0; j < 8; ++j) { e[j] = __expf(pv[8 + j] - mh); sh += e[j]; }
                const float scale = 0.992f / sh;
                float run = 0.f;
                ch[0] = 0.f;
#pragma unroll
                for (int j = 0; j < 8; ++j) { run += 0.001f + e[j] * scale; ch[j + 1] = run; }
                const float icn = 1.0f / fmaxf(ch[8], 1e-12f);
#pragma unroll
                for (int j = 1; j <= 8; ++j) ch[j] *= icn;
            }
#pragma unroll
            for (int j = 0; j < 9; ++j) {
                const float u = pv[16 + j];
                dd[j] = 0.001f + fmaxf(u, 0.f) + log1pf(__expf(-fabsf(u)));
            }

            const float x = inp[(size_t)(row0 + r_e) * 64 + 32 + d];
            const float xs = fminf(fmaxf((x + 10.0f) * 0.05f, 0.f), 1.f);
            int b = 0;
#pragma unroll
            for (int j = 1; j <= 8; ++j) b += (xs >= cw[j]) ? 1 : 0;
            b = min(b, 7);

            float xk = 0.f, wk = 0.f, yk = 0.f, hk = 0.f, dk = 0.f, dk1 = 0.f;
#pragma unroll
            for (int j = 0; j < 8; ++j) {
                if (b == j) {
                    xk = cw[j]; wk = cw[j + 1] - cw[j];
                    yk = ch[j]; hk = ch[j + 1] - ch[j];
                    dk = dd[j]; dk1 = dd[j + 1];
                }
            }

            const float EPSf = 1e-12f;
            const float tt = fminf(fmaxf((xs - xk) / (wk + EPSf), 0.f), 1.f);
            const float a = (hk + EPSf) / (wk + EPSf);
            const float omt = 1.f - tt;
            const float tomt = tt * omt;
            const float num = a * tt * tt + dk * tomt;
            const float den = a + (dk + dk1 - 2.f * a) * tomt;
            const float sres = num / (den + EPSf);
            const float ys = yk + hk * sres;
            float y = ys * 20.0f - 10.0f;
            const float dnum = a * a * (dk1 * tt * tt + 2.f * a * tomt + dk * omt * omt);
            const float dydx = dnum / (den * den + EPSf);
            float lad = __logf(fmaxf(dydx, 1e-12f));

            const bool inside = (x >= -10.0f) && (x <= 10.0f);
            if (!inside) { y = x; lad = 0.0f; }

            out[(size_t)(row0 + r_e) * 64 + 32 + d] = y;
            ladsum += lad;
        }
        __syncthreads();  // before next pass overwrites p_lds
    }

    // ---- logabsdet: reduce across the 16 d-lanes of each row ----
    float s = ladsum;
    s += __shfl_xor(s, 1, 64);
    s += __shfl_xor(s, 2, 64);
    s += __shfl_xor(s, 4, 64);
    s += __shfl_xor(s, 8, 64);
    if (dl == 0) out[(size_t)NROWS * 64 + row0 + r_e] = s;
}

extern "C" void kernel_launch(void* const* d_in, const int* in_sizes, int n_in,
                              void* d_out, int out_size, void* d_ws, size_t ws_size,
                              hipStream_t stream) {
    const float* inp = (const float*)d_in[0];
    const float* W1  = (const float*)d_in[1];
    const float* b1  = (const float*)d_in[2];
    const float* W2  = (const float*)d_in[3];
    const float* b2  = (const float*)d_in[4];
    float* out = (float*)d_out;

    dim3 grid(NROWS / RPB), block(256);
    hipLaunchKernelGGL(rqs_fused, grid, block, 0, stream, inp, W1, b1, W2, b2, out);
}